// Round 13
// baseline (579.906 us; speedup 1.0000x reference)
//
#include <hip/hip_runtime.h>
#include <hip/hip_fp16.h>

// ---------------------------------------------------------------------------
// GIN (2 GINConv layers + linear head) on MI355X.
// Round 13: fuse aggregation INTO the MFMA MLP staging. agg kernels are gone;
// each fused MLP block gathers its 128 nodes' neighbor sums (fp16 table,
// unroll-8) straight into the A-fragment LDS layout, then runs the split-bf16
// MFMA chain. Wins: agg/MLP overlap across concurrent blocks, no Zbuf
// round-trip (~77MB), self-term folded into the gather stream, 13->8 kernels
// (prep+convert+init merged too). CSR build unchanged (R9 form).
// ---------------------------------------------------------------------------

typedef __attribute__((ext_vector_type(8))) short short8;
typedef __attribute__((ext_vector_type(4))) float f32x4;
union F8 { unsigned u[4]; short8 s; };

// pack float -> (lo bf16 << 16) | hi bf16, both RNE
__device__ inline unsigned bfpair(float v) {
    unsigned u = __float_as_uint(v);
    unsigned rh = u + 0x7fffu + ((u >> 16) & 1u);
    unsigned hf = rh & 0xffff0000u;              // hi rounded, as f32 bits
    float lof = v - __uint_as_float(hf);
    unsigned ul = __float_as_uint(lof);
    unsigned rl = ul + 0x7fffu + ((ul >> 16) & 1u);
    return (rh >> 16) | (rl & 0xffff0000u);
}

// ---------------- CSR build (R9 form, unchanged) ----------------

constexpr int BUCKET_SHIFT = 9;
constexpr int BUCKET_NODES = 1 << BUCKET_SHIFT;
constexpr int CAP = 10240;
constexpr int EPB = 4096;
constexpr int NBUCK_MAX = 256;

__global__ __launch_bounds__(256) void bucket_scatter_kernel(const int* __restrict__ ei, int E,
                                                             int* __restrict__ gcur,
                                                             int* __restrict__ gpk,
                                                             int nbuck) {
    __shared__ int spk[EPB];
    __shared__ unsigned char sbuck[EPB];
    __shared__ int lcnt[NBUCK_MAX];
    __shared__ int lbase[NBUCK_MAX];
    __shared__ int lcur[NBUCK_MAX];
    __shared__ int gbase[NBUCK_MAX];
    __shared__ int stmp[256];

    const int t = threadIdx.x;
    const int e0 = blockIdx.x * EPB;
    const int ecnt = min(EPB, E - e0);

    for (int i = t; i < NBUCK_MAX; i += 256) lcnt[i] = 0;
    __syncthreads();

    for (int i = t; i < ecnt; i += 256) {
        int d = ei[E + e0 + i];
        atomicAdd(&lcnt[d >> BUCKET_SHIFT], 1);
    }
    __syncthreads();

    int v = lcnt[t];
    stmp[t] = v;
    __syncthreads();
    #pragma unroll
    for (int off = 1; off < 256; off <<= 1) {
        int add = (t >= off) ? stmp[t - off] : 0;
        __syncthreads();
        stmp[t] += add;
        __syncthreads();
    }
    lbase[t] = stmp[t] - v;
    lcur[t] = stmp[t] - v;
    __syncthreads();

    for (int i = t; i < ecnt; i += 256) {
        int s = ei[e0 + i];
        int d = ei[E + e0 + i];
        int b = d >> BUCKET_SHIFT;
        int p = atomicAdd(&lcur[b], 1);
        spk[p] = ((d & (BUCKET_NODES - 1)) << 17) | s;
        sbuck[p] = (unsigned char)b;
    }
    __syncthreads();

    if (t < nbuck) {
        int c = lcnt[t];
        gbase[t] = (c > 0) ? atomicAdd(&gcur[t], c) : 0;
    }
    __syncthreads();

    for (int i = t; i < ecnt; i += 256) {
        int b = sbuck[i];
        int gp = gbase[b] + (i - lbase[b]);
        if (gp < (b + 1) * CAP) gpk[gp] = spk[i];
    }
}

__global__ __launch_bounds__(256) void bucket_hist_kernel(const int* __restrict__ gpk,
                                                          const int* __restrict__ gcur,
                                                          int* __restrict__ cnt, int N) {
    __shared__ int h[BUCKET_NODES];
    const int t = threadIdx.x;
    const int b = blockIdx.x;
    const int base = b << BUCKET_SHIFT;
    for (int i = t; i < BUCKET_NODES; i += 256) h[i] = 0;
    __syncthreads();
    int cb = min(gcur[b] - b * CAP, CAP);
    const int* pp = gpk + (size_t)b * CAP;
    for (int i = t; i < cb; i += 256) atomicAdd(&h[((unsigned)pp[i]) >> 17], 1);
    __syncthreads();
    for (int i = t; i < BUCKET_NODES && base + i < N; i += 256) cnt[base + i] = h[i];
}

__global__ __launch_bounds__(256) void scan_block_kernel(const int* __restrict__ cnt,
                                                         int* __restrict__ rs,
                                                         int* __restrict__ partials,
                                                         int N) {
    __shared__ int s[256];
    int t = threadIdx.x;
    int i = blockIdx.x * 256 + t;
    int v = (i < N) ? cnt[i] : 0;
    s[t] = v;
    __syncthreads();
    #pragma unroll
    for (int off = 1; off < 256; off <<= 1) {
        int add = (t >= off) ? s[t - off] : 0;
        __syncthreads();
        s[t] += add;
        __syncthreads();
    }
    if (i < N) rs[i] = s[t] - v;
    if (t == 255) partials[blockIdx.x] = s[255];
}

__global__ __launch_bounds__(512) void scan_partials_kernel(int* __restrict__ partials,
                                                            int nb) {
    __shared__ int s[512];
    int t = threadIdx.x;
    int v = (t < nb) ? partials[t] : 0;
    s[t] = v;
    __syncthreads();
    #pragma unroll
    for (int off = 1; off < 512; off <<= 1) {
        int add = (t >= off) ? s[t - off] : 0;
        __syncthreads();
        s[t] += add;
        __syncthreads();
    }
    if (t < nb) partials[t] = s[t] - v;
}

__global__ __launch_bounds__(256) void scan_add_kernel(int* __restrict__ rs,
                                                       const int* __restrict__ partials,
                                                       int N, int E) {
    int i = blockIdx.x * 256 + threadIdx.x;
    if (i < N) rs[i] += partials[blockIdx.x];
    if (i == 0) rs[N] = E;
}

__global__ __launch_bounds__(256) void bucket_fill_kernel(const int* __restrict__ gpk,
                                                          const int* __restrict__ gcur,
                                                          const int* __restrict__ rs,
                                                          int* __restrict__ edge_src, int N) {
    __shared__ int cur[BUCKET_NODES];
    const int t = threadIdx.x;
    const int b = blockIdx.x;
    const int base = b << BUCKET_SHIFT;
    for (int i = t; i < BUCKET_NODES; i += 256) cur[i] = rs[min(base + i, N)];
    __syncthreads();
    int cb = min(gcur[b] - b * CAP, CAP);
    const int* pp = gpk + (size_t)b * CAP;
    for (int i = t; i < cb; i += 256) {
        unsigned pw = (unsigned)pp[i];
        int p = atomicAdd(&cur[pw >> 17], 1);
        edge_src[p] = (int)(pw & 0x1FFFFu);
    }
}

// ---------------- merged prep: weights + x->fp16 + gcur init ----------------
// grid = 12500 blocks; blocks also grid-stride the x conversion.

__global__ __launch_bounds__(256) void prep_kernel(const float* __restrict__ W1a,
                                                   const float* __restrict__ W1b,
                                                   const float* __restrict__ W2a,
                                                   const float* __restrict__ W2b,
                                                   const float* __restrict__ Wlin,
                                                   short* __restrict__ hi,
                                                   short* __restrict__ lo,
                                                   const float* __restrict__ x,
                                                   __half2* __restrict__ x16, int n2,
                                                   int* __restrict__ gcur, int nbuck) {
    int i = blockIdx.x * 256 + threadIdx.x;
    if (blockIdx.x == 0 && threadIdx.x < nbuck) gcur[threadIdx.x] = threadIdx.x * CAP;
    if (i < 65536) {
        const float* W;
        int base, K, N;
        if (i < 8192)       { W = W1a;  base = 0;     K = 64;  N = 128; }
        else if (i < 24576) { W = W1b;  base = 8192;  K = 128; N = 128; }
        else if (i < 40960) { W = W2a;  base = 24576; K = 128; N = 128; }
        else if (i < 57344) { W = W2b;  base = 40960; K = 128; N = 128; }
        else                { W = Wlin; base = 57344; K = 128; N = 64;  }
        int rel = i - base;
        int NT = N >> 4;
        int j  = rel & 7;
        int l  = (rel >> 3) & 63;
        int tc = rel >> 9;            // c*NT + nt
        int nt = tc % NT;
        int c  = tc / NT;
        int n  = nt * 16 + (l & 15);
        int k  = c * 32 + ((l >> 4) << 3) + j;
        float v = W[k * N + n];
        unsigned p = bfpair(v);
        hi[i] = (short)(p & 0xffffu);
        lo[i] = (short)(p >> 16);
    }
    for (int k = i; k < n2; k += gridDim.x * 256) {
        float2 v = reinterpret_cast<const float2*>(x)[k];
        x16[k] = __floats2half2_rn(v.x, v.y);
    }
}

// ---------------- fused gather->A-fragment staging --------------------------
// Writes the summed node row directly into P's A-frag layout:
// P[((T*KC + c)*8 + j)*66 + l'] = A[T*16 + (l'&15)][c*32 + (l'>>4)*8 + j].
// Lane covers cols (2l, 2l+1): c=l>>4(K128)/cl>>4(K64), j0=2*(l&3),
// q2=(l>>2)&3, l'=(q2<<4)|(r&15).  (c*32+q2*8+j0 == 2l, verified.)

// K=128 (KC=4): 64 lanes = 64 half2 cols; wave w gathers rows [w*32,w*32+32).
__device__ inline void stage_agg128(const __half2* __restrict__ H16,
                                    const int* __restrict__ row_start,
                                    const int* __restrict__ edge_src,
                                    int M, int m0, unsigned* __restrict__ P,
                                    int w, int lane) {
    const int c  = lane >> 4;
    const int j0 = 2 * (lane & 3);
    const int q2 = (lane >> 2) & 3;
    for (int r = w * 32; r < w * 32 + 32; ++r) {
        int node = m0 + r;
        if (node >= M) break;                     // wave-uniform
        int beg = row_start[node], end = row_start[node + 1];
        float2 self = __half22float2(H16[(size_t)node * 64 + lane]);
        float a0 = self.x, a1 = self.y;
        int i = beg;
        for (; i + 8 <= end; i += 8) {
            int s[8];
            #pragma unroll
            for (int j = 0; j < 8; ++j) s[j] = edge_src[i + j];
            float2 v[8];
            #pragma unroll
            for (int j = 0; j < 8; ++j) v[j] = __half22float2(H16[(size_t)s[j] * 64 + lane]);
            #pragma unroll
            for (int j = 0; j < 8; ++j) { a0 += v[j].x; a1 += v[j].y; }
        }
        for (; i < end; ++i) {
            float2 v = __half22float2(H16[(size_t)edge_src[i] * 64 + lane]);
            a0 += v.x; a1 += v.y;
        }
        int pb = (((r >> 4) * 4 + c) * 8 + j0) * 66 + ((q2 << 4) | (r & 15));
        P[pb]      = bfpair(a0);
        P[pb + 66] = bfpair(a1);
    }
}

// K=64 (KC=2): half-wave per node (lanes 0-31 / 32-63), 2 nodes per step.
__device__ inline void stage_agg64(const __half2* __restrict__ H16,
                                   const int* __restrict__ row_start,
                                   const int* __restrict__ edge_src,
                                   int M, int m0, unsigned* __restrict__ P,
                                   int w, int lane) {
    const int sub = lane >> 5;
    const int cl  = lane & 31;
    const int c   = cl >> 4;
    const int j0  = 2 * (cl & 3);
    const int q2  = (cl >> 2) & 3;
    for (int rp = w * 32; rp < w * 32 + 32; rp += 2) {
        int r = rp + sub;
        int node = m0 + r;
        if (node < M) {
            int beg = row_start[node], end = row_start[node + 1];
            float2 self = __half22float2(H16[(size_t)node * 32 + cl]);
            float a0 = self.x, a1 = self.y;
            int i = beg;
            for (; i + 8 <= end; i += 8) {
                int s[8];
                #pragma unroll
                for (int j = 0; j < 8; ++j) s[j] = edge_src[i + j];
                float2 v[8];
                #pragma unroll
                for (int j = 0; j < 8; ++j) v[j] = __half22float2(H16[(size_t)s[j] * 32 + cl]);
                #pragma unroll
                for (int j = 0; j < 8; ++j) { a0 += v[j].x; a1 += v[j].y; }
            }
            for (; i < end; ++i) {
                float2 v = __half22float2(H16[(size_t)edge_src[i] * 32 + cl]);
                a0 += v.x; a1 += v.y;
            }
            int pb = (((r >> 4) * 2 + c) * 8 + j0) * 66 + ((q2 << 4) | (r & 15));
            P[pb]      = bfpair(a0);
            P[pb + 66] = bfpair(a1);
        }
    }
}

// ---------------- MFMA compute/epilogue (unchanged from R9/R12) -------------

template <int K, int NT>
__device__ inline void stage_compute(const unsigned* __restrict__ P,
                                     const short* __restrict__ WH,
                                     const short* __restrict__ WL,
                                     int w, int lane, f32x4 (*acc)[8]) {
    constexpr int KC = K / 32;
    const short8* bhp = reinterpret_cast<const short8*>(WH) + lane;
    const short8* blp = reinterpret_cast<const short8*>(WL) + lane;
    for (int c = 0; c < KC; ++c) {
        F8 bh[NT], bl[NT];
        #pragma unroll
        for (int nt = 0; nt < NT; ++nt) {
            bh[nt].s = bhp[(c * NT + nt) * 64];
            bl[nt].s = blp[(c * NT + nt) * 64];
        }
        #pragma unroll
        for (int mt = 0; mt < 2; ++mt) {
            const int T = w * 2 + mt;
            const unsigned* Pb = P + ((T * KC + c) * 8) * 66 + lane;
            unsigned d[8];
            #pragma unroll
            for (int j = 0; j < 8; ++j) d[j] = Pb[j * 66];
            F8 ah, al;
            #pragma unroll
            for (int j = 0; j < 4; ++j) {
                ah.u[j] = __builtin_amdgcn_perm(d[2 * j + 1], d[2 * j], 0x05040100u);
                al.u[j] = __builtin_amdgcn_perm(d[2 * j + 1], d[2 * j], 0x07060302u);
            }
            #pragma unroll
            for (int nt = 0; nt < NT; ++nt) {
                acc[mt][nt] = __builtin_amdgcn_mfma_f32_16x16x32_bf16(ah.s, bh[nt].s, acc[mt][nt], 0, 0, 0);
                acc[mt][nt] = __builtin_amdgcn_mfma_f32_16x16x32_bf16(al.s, bh[nt].s, acc[mt][nt], 0, 0, 0);
                acc[mt][nt] = __builtin_amdgcn_mfma_f32_16x16x32_bf16(ah.s, bl[nt].s, acc[mt][nt], 0, 0, 0);
            }
        }
    }
}

__device__ inline void epilogue_tile(const f32x4* acc, const float* __restrict__ bias,
                                     unsigned* __restrict__ Pout, int T, int lane) {
    int q = lane >> 4, ln = lane & 15;
    #pragma unroll
    for (int nt = 0; nt < 8; ++nt) {
        int col = nt * 16 + ln;
        float b = bias[col];
        int c = col >> 5, jj = col & 7, q2 = (col >> 3) & 3;
        int pb = ((T * 4 + c) * 8 + jj) * 66;
        #pragma unroll
        for (int r = 0; r < 4; ++r) {
            float v = fmaxf(acc[nt][r] + b, 0.f);
            Pout[pb + ((q * 4 + r) | (q2 << 4))] = bfpair(v);
        }
    }
}

// conv1 fused: gather(x16) -> relu(relu(z@Wa+ba)@Wb+bb) = h1 (fp16)
__global__ __launch_bounds__(256, 2) void fused_mlp_A(const __half2* __restrict__ x16,
                                                      const int* __restrict__ row_start,
                                                      const int* __restrict__ edge_src,
                                                      const short* __restrict__ WaH,
                                                      const short* __restrict__ WaL,
                                                      const float* __restrict__ ba,
                                                      const short* __restrict__ WbH,
                                                      const short* __restrict__ WbL,
                                                      const float* __restrict__ bb,
                                                      __half* __restrict__ H16out, int M) {
    __shared__ unsigned P[8 * 4 * 8 * 66];   // 67584 B
    const int t = threadIdx.x;
    const int w = t >> 6, lane = t & 63;
    const int m0 = blockIdx.x * 128;
    const int q = lane >> 4, ln = lane & 15;

    stage_agg64(x16, row_start, edge_src, M, m0, P, w, lane);
    __syncthreads();

    f32x4 acc[2][8];
    #pragma unroll
    for (int mt = 0; mt < 2; ++mt)
        #pragma unroll
        for (int i = 0; i < 8; ++i) acc[mt][i] = (f32x4){0.f, 0.f, 0.f, 0.f};
    stage_compute<64, 8>(P, WaH, WaL, w, lane, acc);
    __syncthreads();
    epilogue_tile(acc[0], ba, P, w * 2 + 0, lane);
    epilogue_tile(acc[1], ba, P, w * 2 + 1, lane);
    __syncthreads();

    #pragma unroll
    for (int mt = 0; mt < 2; ++mt)
        #pragma unroll
        for (int i = 0; i < 8; ++i) acc[mt][i] = (f32x4){0.f, 0.f, 0.f, 0.f};
    stage_compute<128, 8>(P, WbH, WbL, w, lane, acc);

    #pragma unroll
    for (int mt = 0; mt < 2; ++mt) {
        #pragma unroll
        for (int nt = 0; nt < 8; ++nt) {
            int col = nt * 16 + ln;
            float b = bb[col];
            #pragma unroll
            for (int r = 0; r < 4; ++r) {
                int row = m0 + (w * 2 + mt) * 16 + q * 4 + r;
                if (row < M) {
                    float v = fmaxf(acc[mt][nt][r] + b, 0.f);
                    H16out[(size_t)row * 128 + col] = __float2half_rn(v);
                }
            }
        }
    }
}

// conv2+head fused: gather(h116) -> (relu(relu(z@Wa+ba)@Wb+bb))@Wl+bl = out
__global__ __launch_bounds__(256, 2) void fused_mlp_B(const __half2* __restrict__ h116,
                                                      const int* __restrict__ row_start,
                                                      const int* __restrict__ edge_src,
                                                      const short* __restrict__ WaH,
                                                      const short* __restrict__ WaL,
                                                      const float* __restrict__ ba,
                                                      const short* __restrict__ WbH,
                                                      const short* __restrict__ WbL,
                                                      const float* __restrict__ bb,
                                                      const short* __restrict__ WlH,
                                                      const short* __restrict__ WlL,
                                                      const float* __restrict__ bl,
                                                      float* __restrict__ Out, int M) {
    __shared__ unsigned P[8 * 4 * 8 * 66];   // 67584 B
    const int t = threadIdx.x;
    const int w = t >> 6, lane = t & 63;
    const int m0 = blockIdx.x * 128;
    const int q = lane >> 4, ln = lane & 15;

    stage_agg128(h116, row_start, edge_src, M, m0, P, w, lane);
    __syncthreads();

    f32x4 acc[2][8];
    #pragma unroll
    for (int mt = 0; mt < 2; ++mt)
        #pragma unroll
        for (int i = 0; i < 8; ++i) acc[mt][i] = (f32x4){0.f, 0.f, 0.f, 0.f};
    stage_compute<128, 8>(P, WaH, WaL, w, lane, acc);
    __syncthreads();
    epilogue_tile(acc[0], ba, P, w * 2 + 0, lane);
    epilogue_tile(acc[1], ba, P, w * 2 + 1, lane);
    __syncthreads();

    #pragma unroll
    for (int mt = 0; mt < 2; ++mt)
        #pragma unroll
        for (int i = 0; i < 8; ++i) acc[mt][i] = (f32x4){0.f, 0.f, 0.f, 0.f};
    stage_compute<128, 8>(P, WbH, WbL, w, lane, acc);
    __syncthreads();
    epilogue_tile(acc[0], bb, P, w * 2 + 0, lane);
    epilogue_tile(acc[1], bb, P, w * 2 + 1, lane);
    __syncthreads();

    #pragma unroll
    for (int mt = 0; mt < 2; ++mt)
        #pragma unroll
        for (int i = 0; i < 8; ++i) acc[mt][i] = (f32x4){0.f, 0.f, 0.f, 0.f};
    stage_compute<128, 4>(P, WlH, WlL, w, lane, acc);

    #pragma unroll
    for (int mt = 0; mt < 2; ++mt) {
        #pragma unroll
        for (int nt = 0; nt < 4; ++nt) {
            int col = nt * 16 + ln;
            float b = bl[col];
            #pragma unroll
            for (int r = 0; r < 4; ++r) {
                int row = m0 + (w * 2 + mt) * 16 + q * 4 + r;
                if (row < M) Out[(size_t)row * 64 + col] = acc[mt][nt][r] + b;
            }
        }
    }
}

// ---------------------------------------------------------------------------

extern "C" void kernel_launch(void* const* d_in, const int* in_sizes, int n_in,
                              void* d_out, int out_size, void* d_ws, size_t ws_size,
                              hipStream_t stream) {
    const float* x    = (const float*)d_in[0];
    const int*   ei   = (const int*)d_in[1];
    const float* W1a  = (const float*)d_in[2];
    const float* b1a  = (const float*)d_in[3];
    const float* W1b  = (const float*)d_in[4];
    const float* b1b  = (const float*)d_in[5];
    const float* W2a  = (const float*)d_in[6];
    const float* b2a  = (const float*)d_in[7];
    const float* W2b  = (const float*)d_in[8];
    const float* b2b  = (const float*)d_in[9];
    const float* Wlin = (const float*)d_in[10];
    const float* blin = (const float*)d_in[11];
    float* out = (float*)d_out;

    const int N = in_sizes[0] / 64;   // 100000
    const int E = in_sizes[1] / 2;    // 1600000
    const int NBUCK = (N + BUCKET_NODES - 1) >> BUCKET_SHIFT;  // 196

    // workspace layout
    char* ws = (char*)d_ws;
    const size_t bufBytes = (size_t)N * 128 * sizeof(float);  // 51.2 MB
    char* B = ws + bufBytes;
    size_t off = 3 * bufBytes;
    int* row_start = (int*)(ws + off); off += ((size_t)(N + 1) * 4 + 15) & ~(size_t)15;
    int* cnt       = (int*)(ws + off); off += ((size_t)N * 4 + 15) & ~(size_t)15;
    int* partials  = (int*)(ws + off); off += 4096;
    int* gcur      = (int*)(ws + off); off += 4096;
    int* edge_src  = (int*)(ws + off); off += (size_t)E * 4;
    __half* h116   = (__half*)(ws + off); off += (size_t)N * 128 * 2;  // 25.6 MB
    // B-buffer interior aliases:
    int* gpk = (int*)B;                              // [0 .. 8MB)
    short* wHi = (short*)(B + (32u << 20));
    short* wLo = wHi + 65536;
    __half* x16 = (__half*)(B + (36u << 20));
    short* w1aH = wHi + 0;     short* w1aL = wLo + 0;
    short* w1bH = wHi + 8192;  short* w1bL = wLo + 8192;
    short* w2aH = wHi + 24576; short* w2aL = wLo + 24576;
    short* w2bH = wHi + 40960; short* w2bL = wLo + 40960;
    short* wlH  = wHi + 57344; short* wlL  = wLo + 57344;

    const int NB_N = (N + 255) / 256;          // 391
    const int NB_G = (N + 127) / 128;          // 782 fused-MLP blocks
    const int NB_S = (E + EPB - 1) / EPB;      // 391 scatter blocks
    const int NB_P = 12500;                    // prep/convert blocks

    // 0. merged prep: weights, x->fp16, gcur init
    prep_kernel<<<NB_P, 256, 0, stream>>>(W1a, W1b, W2a, W2b, Wlin, wHi, wLo,
                                          x, (__half2*)x16, N * 32, gcur, NBUCK);

    // 1. CSR build, bucket-binned, packed staging
    bucket_scatter_kernel<<<NB_S, 256, 0, stream>>>(ei, E, gcur, gpk, NBUCK);
    bucket_hist_kernel<<<NBUCK, 256, 0, stream>>>(gpk, gcur, cnt, N);
    scan_block_kernel<<<NB_N, 256, 0, stream>>>(cnt, row_start, partials, N);
    scan_partials_kernel<<<1, 512, 0, stream>>>(partials, NB_N);
    scan_add_kernel<<<NB_N, 256, 0, stream>>>(row_start, partials, N, E);
    bucket_fill_kernel<<<NBUCK, 256, 0, stream>>>(gpk, gcur, row_start, edge_src, N);

    // 2. conv1: fused gather + MLP -> h1 (fp16)
    fused_mlp_A<<<NB_G, 256, 0, stream>>>((const __half2*)x16, row_start, edge_src,
                                          w1aH, w1aL, b1a, w1bH, w1bL, b1b, h116, N);

    // 3. conv2 + head: fused gather + MLP -> out
    fused_mlp_B<<<NB_G, 256, 0, stream>>>((const __half2*)h116, row_start, edge_src,
                                          w2aH, w2aL, b2a, w2bH, w2bL, b2b,
                                          wlH, wlL, blin, out, N);
}

// Round 15
// 363.153 us; speedup vs baseline: 1.5969x; 1.5969x over previous
//
#include <hip/hip_runtime.h>
#include <hip/hip_fp16.h>

// ---------------------------------------------------------------------------
// GIN (2 GINConv layers + linear head) on MI355X.
// Round 15 (= R14 resubmit after broker timeout): restore R9 (best measured:
// 367.8us). R13's agg-into-MLP fusion starved the gather of wave parallelism
// (occupancy 17% -> 1.1TB/s); split memory-bound agg kernels restored.
// Keeps R13's merged prep launch.
//   - CSR: bucket-binned packed staging, LDS-local hist/fill (R9)
//   - agg: fp16 table + fp16 z, unroll-4 (R9)
//   - MLPs: 128-row blocks, 2 m-tiles/wave, split-bf16 MFMA,
//     fragment-interleaved weights (R9)
// ---------------------------------------------------------------------------

typedef __attribute__((ext_vector_type(8))) short short8;
typedef __attribute__((ext_vector_type(4))) float f32x4;
union F8 { unsigned u[4]; short8 s; };

// pack float -> (lo bf16 << 16) | hi bf16, both RNE
__device__ inline unsigned bfpair(float v) {
    unsigned u = __float_as_uint(v);
    unsigned rh = u + 0x7fffu + ((u >> 16) & 1u);
    unsigned hf = rh & 0xffff0000u;              // hi rounded, as f32 bits
    float lof = v - __uint_as_float(hf);
    unsigned ul = __float_as_uint(lof);
    unsigned rl = ul + 0x7fffu + ((ul >> 16) & 1u);
    return (rh >> 16) | (rl & 0xffff0000u);
}

// ---------------- CSR build (R9 form) ----------------

constexpr int BUCKET_SHIFT = 9;
constexpr int BUCKET_NODES = 1 << BUCKET_SHIFT;
constexpr int CAP = 10240;
constexpr int EPB = 4096;
constexpr int NBUCK_MAX = 256;

__global__ __launch_bounds__(256) void bucket_scatter_kernel(const int* __restrict__ ei, int E,
                                                             int* __restrict__ gcur,
                                                             int* __restrict__ gpk,
                                                             int nbuck) {
    __shared__ int spk[EPB];
    __shared__ unsigned char sbuck[EPB];
    __shared__ int lcnt[NBUCK_MAX];
    __shared__ int lbase[NBUCK_MAX];
    __shared__ int lcur[NBUCK_MAX];
    __shared__ int gbase[NBUCK_MAX];
    __shared__ int stmp[256];

    const int t = threadIdx.x;
    const int e0 = blockIdx.x * EPB;
    const int ecnt = min(EPB, E - e0);

    for (int i = t; i < NBUCK_MAX; i += 256) lcnt[i] = 0;
    __syncthreads();

    for (int i = t; i < ecnt; i += 256) {
        int d = ei[E + e0 + i];
        atomicAdd(&lcnt[d >> BUCKET_SHIFT], 1);
    }
    __syncthreads();

    int v = lcnt[t];
    stmp[t] = v;
    __syncthreads();
    #pragma unroll
    for (int off = 1; off < 256; off <<= 1) {
        int add = (t >= off) ? stmp[t - off] : 0;
        __syncthreads();
        stmp[t] += add;
        __syncthreads();
    }
    lbase[t] = stmp[t] - v;
    lcur[t] = stmp[t] - v;
    __syncthreads();

    for (int i = t; i < ecnt; i += 256) {
        int s = ei[e0 + i];
        int d = ei[E + e0 + i];
        int b = d >> BUCKET_SHIFT;
        int p = atomicAdd(&lcur[b], 1);
        spk[p] = ((d & (BUCKET_NODES - 1)) << 17) | s;
        sbuck[p] = (unsigned char)b;
    }
    __syncthreads();

    if (t < nbuck) {
        int c = lcnt[t];
        gbase[t] = (c > 0) ? atomicAdd(&gcur[t], c) : 0;
    }
    __syncthreads();

    for (int i = t; i < ecnt; i += 256) {
        int b = sbuck[i];
        int gp = gbase[b] + (i - lbase[b]);
        if (gp < (b + 1) * CAP) gpk[gp] = spk[i];
    }
}

__global__ __launch_bounds__(256) void bucket_hist_kernel(const int* __restrict__ gpk,
                                                          const int* __restrict__ gcur,
                                                          int* __restrict__ cnt, int N) {
    __shared__ int h[BUCKET_NODES];
    const int t = threadIdx.x;
    const int b = blockIdx.x;
    const int base = b << BUCKET_SHIFT;
    for (int i = t; i < BUCKET_NODES; i += 256) h[i] = 0;
    __syncthreads();
    int cb = min(gcur[b] - b * CAP, CAP);
    const int* pp = gpk + (size_t)b * CAP;
    for (int i = t; i < cb; i += 256) atomicAdd(&h[((unsigned)pp[i]) >> 17], 1);
    __syncthreads();
    for (int i = t; i < BUCKET_NODES && base + i < N; i += 256) cnt[base + i] = h[i];
}

__global__ __launch_bounds__(256) void scan_block_kernel(const int* __restrict__ cnt,
                                                         int* __restrict__ rs,
                                                         int* __restrict__ partials,
                                                         int N) {
    __shared__ int s[256];
    int t = threadIdx.x;
    int i = blockIdx.x * 256 + t;
    int v = (i < N) ? cnt[i] : 0;
    s[t] = v;
    __syncthreads();
    #pragma unroll
    for (int off = 1; off < 256; off <<= 1) {
        int add = (t >= off) ? s[t - off] : 0;
        __syncthreads();
        s[t] += add;
        __syncthreads();
    }
    if (i < N) rs[i] = s[t] - v;
    if (t == 255) partials[blockIdx.x] = s[255];
}

__global__ __launch_bounds__(512) void scan_partials_kernel(int* __restrict__ partials,
                                                            int nb) {
    __shared__ int s[512];
    int t = threadIdx.x;
    int v = (t < nb) ? partials[t] : 0;
    s[t] = v;
    __syncthreads();
    #pragma unroll
    for (int off = 1; off < 512; off <<= 1) {
        int add = (t >= off) ? s[t - off] : 0;
        __syncthreads();
        s[t] += add;
        __syncthreads();
    }
    if (t < nb) partials[t] = s[t] - v;
}

__global__ __launch_bounds__(256) void scan_add_kernel(int* __restrict__ rs,
                                                       const int* __restrict__ partials,
                                                       int N, int E) {
    int i = blockIdx.x * 256 + threadIdx.x;
    if (i < N) rs[i] += partials[blockIdx.x];
    if (i == 0) rs[N] = E;
}

__global__ __launch_bounds__(256) void bucket_fill_kernel(const int* __restrict__ gpk,
                                                          const int* __restrict__ gcur,
                                                          const int* __restrict__ rs,
                                                          int* __restrict__ edge_src, int N) {
    __shared__ int cur[BUCKET_NODES];
    const int t = threadIdx.x;
    const int b = blockIdx.x;
    const int base = b << BUCKET_SHIFT;
    for (int i = t; i < BUCKET_NODES; i += 256) cur[i] = rs[min(base + i, N)];
    __syncthreads();
    int cb = min(gcur[b] - b * CAP, CAP);
    const int* pp = gpk + (size_t)b * CAP;
    for (int i = t; i < cb; i += 256) {
        unsigned pw = (unsigned)pp[i];
        int p = atomicAdd(&cur[pw >> 17], 1);
        edge_src[p] = (int)(pw & 0x1FFFFu);
    }
}

// ---------------- merged prep: weights + x->fp16 + gcur init ----------------

__global__ __launch_bounds__(256) void prep_kernel(const float* __restrict__ W1a,
                                                   const float* __restrict__ W1b,
                                                   const float* __restrict__ W2a,
                                                   const float* __restrict__ W2b,
                                                   const float* __restrict__ Wlin,
                                                   short* __restrict__ hi,
                                                   short* __restrict__ lo,
                                                   const float* __restrict__ x,
                                                   __half2* __restrict__ x16, int n2,
                                                   int* __restrict__ gcur, int nbuck) {
    int i = blockIdx.x * 256 + threadIdx.x;
    if (blockIdx.x == 0 && threadIdx.x < nbuck) gcur[threadIdx.x] = threadIdx.x * CAP;
    if (i < 65536) {
        const float* W;
        int base, K, N;
        if (i < 8192)       { W = W1a;  base = 0;     K = 64;  N = 128; }
        else if (i < 24576) { W = W1b;  base = 8192;  K = 128; N = 128; }
        else if (i < 40960) { W = W2a;  base = 24576; K = 128; N = 128; }
        else if (i < 57344) { W = W2b;  base = 40960; K = 128; N = 128; }
        else                { W = Wlin; base = 57344; K = 128; N = 64;  }
        int rel = i - base;
        int NT = N >> 4;
        int j  = rel & 7;
        int l  = (rel >> 3) & 63;
        int tc = rel >> 9;            // c*NT + nt
        int nt = tc % NT;
        int c  = tc / NT;
        int n  = nt * 16 + (l & 15);
        int k  = c * 32 + ((l >> 4) << 3) + j;
        float v = W[k * N + n];
        unsigned p = bfpair(v);
        hi[i] = (short)(p & 0xffffu);
        lo[i] = (short)(p >> 16);
    }
    for (int k = i; k < n2; k += gridDim.x * 256) {
        float2 v = reinterpret_cast<const float2*>(x)[k];
        x16[k] = __floats2half2_rn(v.x, v.y);
    }
}

// ---------------- aggregation (R9 form, unroll-4) ----------------

// Z16[i] = fp16( fp16(H[i]) + sum_j fp16(H[src_j]) );  D=128, one wave/node.
__global__ __launch_bounds__(256) void agg128_fp16(const __half2* __restrict__ H16,
                                                   const int* __restrict__ row_start,
                                                   const int* __restrict__ edge_src,
                                                   __half2* __restrict__ Z16, int N) {
    int wave = threadIdx.x >> 6, lane = threadIdx.x & 63;
    int node = blockIdx.x * 4 + wave;
    if (node >= N) return;
    int beg = row_start[node], end = row_start[node + 1];
    float2 self = __half22float2(H16[(size_t)node * 64 + lane]);
    float a0 = self.x, a1 = self.y;
    int i = beg;
    for (; i + 4 <= end; i += 4) {
        int s0 = edge_src[i], s1 = edge_src[i + 1];
        int s2 = edge_src[i + 2], s3 = edge_src[i + 3];
        float2 v0 = __half22float2(H16[(size_t)s0 * 64 + lane]);
        float2 v1 = __half22float2(H16[(size_t)s1 * 64 + lane]);
        float2 v2 = __half22float2(H16[(size_t)s2 * 64 + lane]);
        float2 v3 = __half22float2(H16[(size_t)s3 * 64 + lane]);
        a0 += (v0.x + v1.x) + (v2.x + v3.x);
        a1 += (v0.y + v1.y) + (v2.y + v3.y);
    }
    for (; i < end; ++i) {
        float2 v = __half22float2(H16[(size_t)edge_src[i] * 64 + lane]);
        a0 += v.x;
        a1 += v.y;
    }
    Z16[(size_t)node * 64 + lane] = __floats2half2_rn(a0, a1);
}

// D=64: two nodes per wave (32-lane groups, 128B coalesced gathers).
__global__ __launch_bounds__(256) void agg64_fp16(const __half2* __restrict__ H16,
                                                  const int* __restrict__ row_start,
                                                  const int* __restrict__ edge_src,
                                                  __half2* __restrict__ Z16, int N) {
    int t = threadIdx.x;
    int grp = t >> 5;          // 0..7
    int gl = t & 31;
    int node = blockIdx.x * 8 + grp;
    if (node >= N) return;
    int beg = row_start[node], end = row_start[node + 1];
    float2 self = __half22float2(H16[(size_t)node * 32 + gl]);
    float a0 = self.x, a1 = self.y;
    int i = beg;
    for (; i + 4 <= end; i += 4) {
        int s0 = edge_src[i], s1 = edge_src[i + 1];
        int s2 = edge_src[i + 2], s3 = edge_src[i + 3];
        float2 v0 = __half22float2(H16[(size_t)s0 * 32 + gl]);
        float2 v1 = __half22float2(H16[(size_t)s1 * 32 + gl]);
        float2 v2 = __half22float2(H16[(size_t)s2 * 32 + gl]);
        float2 v3 = __half22float2(H16[(size_t)s3 * 32 + gl]);
        a0 += (v0.x + v1.x) + (v2.x + v3.x);
        a1 += (v0.y + v1.y) + (v2.y + v3.y);
    }
    for (; i < end; ++i) {
        float2 v = __half22float2(H16[(size_t)edge_src[i] * 32 + gl]);
        a0 += v.x;
        a1 += v.y;
    }
    Z16[(size_t)node * 32 + gl] = __floats2half2_rn(a0, a1);
}

// ---------------- MFMA fused MLP (128 rows/block, 2 m-tiles/wave) -----------

template <int K>
__device__ inline void stage_global16(const __half2* __restrict__ z, int M, int m0,
                                      unsigned* __restrict__ P, int t) {
    constexpr int KC = K / 32;
    constexpr int NF = 8 * KC * 64;
    #pragma unroll
    for (int fi = t; fi < NF; fi += 256) {
        int l = fi & 63;
        int tc = fi >> 6;
        int c = tc & (KC - 1);
        int T = tc / KC;
        int row = m0 + T * 16 + (l & 15);
        if (row >= M) row = M - 1;
        int kb = c * 32 + ((l >> 4) << 3);   // multiple of 8
        const __half2* p = z + (size_t)row * (K / 2) + (kb >> 1);
        uint4 v = *reinterpret_cast<const uint4*>(p);  // 8 halves
        float2 f0 = __half22float2(*reinterpret_cast<__half2*>(&v.x));
        float2 f1 = __half22float2(*reinterpret_cast<__half2*>(&v.y));
        float2 f2 = __half22float2(*reinterpret_cast<__half2*>(&v.z));
        float2 f3 = __half22float2(*reinterpret_cast<__half2*>(&v.w));
        int base = ((T * KC + c) * 8) * 66 + l;
        P[base + 0 * 66] = bfpair(f0.x);
        P[base + 1 * 66] = bfpair(f0.y);
        P[base + 2 * 66] = bfpair(f1.x);
        P[base + 3 * 66] = bfpair(f1.y);
        P[base + 4 * 66] = bfpair(f2.x);
        P[base + 5 * 66] = bfpair(f2.y);
        P[base + 6 * 66] = bfpair(f3.x);
        P[base + 7 * 66] = bfpair(f3.y);
    }
}

template <int K, int NT>
__device__ inline void stage_compute(const unsigned* __restrict__ P,
                                     const short* __restrict__ WH,
                                     const short* __restrict__ WL,
                                     int w, int lane, f32x4 (*acc)[8]) {
    constexpr int KC = K / 32;
    const short8* bhp = reinterpret_cast<const short8*>(WH) + lane;
    const short8* blp = reinterpret_cast<const short8*>(WL) + lane;
    for (int c = 0; c < KC; ++c) {
        F8 bh[NT], bl[NT];
        #pragma unroll
        for (int nt = 0; nt < NT; ++nt) {
            bh[nt].s = bhp[(c * NT + nt) * 64];
            bl[nt].s = blp[(c * NT + nt) * 64];
        }
        #pragma unroll
        for (int mt = 0; mt < 2; ++mt) {
            const int T = w * 2 + mt;
            const unsigned* Pb = P + ((T * KC + c) * 8) * 66 + lane;
            unsigned d[8];
            #pragma unroll
            for (int j = 0; j < 8; ++j) d[j] = Pb[j * 66];
            F8 ah, al;
            #pragma unroll
            for (int j = 0; j < 4; ++j) {
                ah.u[j] = __builtin_amdgcn_perm(d[2 * j + 1], d[2 * j], 0x05040100u);
                al.u[j] = __builtin_amdgcn_perm(d[2 * j + 1], d[2 * j], 0x07060302u);
            }
            #pragma unroll
            for (int nt = 0; nt < NT; ++nt) {
                acc[mt][nt] = __builtin_amdgcn_mfma_f32_16x16x32_bf16(ah.s, bh[nt].s, acc[mt][nt], 0, 0, 0);
                acc[mt][nt] = __builtin_amdgcn_mfma_f32_16x16x32_bf16(al.s, bh[nt].s, acc[mt][nt], 0, 0, 0);
                acc[mt][nt] = __builtin_amdgcn_mfma_f32_16x16x32_bf16(ah.s, bl[nt].s, acc[mt][nt], 0, 0, 0);
            }
        }
    }
}

__device__ inline void epilogue_tile(const f32x4* acc, const float* __restrict__ bias,
                                     unsigned* __restrict__ Pout, int T, int lane) {
    int q = lane >> 4, ln = lane & 15;
    #pragma unroll
    for (int nt = 0; nt < 8; ++nt) {
        int col = nt * 16 + ln;
        float b = bias[col];
        int c = col >> 5, jj = col & 7, q2 = (col >> 3) & 3;
        int pb = ((T * 4 + c) * 8 + jj) * 66;
        #pragma unroll
        for (int r = 0; r < 4; ++r) {
            float v = fmaxf(acc[nt][r] + b, 0.f);
            Pout[pb + ((q * 4 + r) | (q2 << 4))] = bfpair(v);
        }
    }
}

// conv1 MLP: z16[M,64] -> relu(relu(z@Wa+ba)@Wb+bb) = h1 (fp16)
__global__ __launch_bounds__(256, 2) void mfma_mlp_A(const __half2* __restrict__ z16,
                                                     const short* __restrict__ WaH,
                                                     const short* __restrict__ WaL,
                                                     const float* __restrict__ ba,
                                                     const short* __restrict__ WbH,
                                                     const short* __restrict__ WbL,
                                                     const float* __restrict__ bb,
                                                     __half* __restrict__ H16out, int M) {
    __shared__ unsigned P[8 * 4 * 8 * 66];   // 67584 B
    const int t = threadIdx.x;
    const int w = t >> 6, lane = t & 63;
    const int m0 = blockIdx.x * 128;
    const int q = lane >> 4, ln = lane & 15;

    stage_global16<64>(z16, M, m0, P, t);
    __syncthreads();

    f32x4 acc[2][8];
    #pragma unroll
    for (int mt = 0; mt < 2; ++mt)
        #pragma unroll
        for (int i = 0; i < 8; ++i) acc[mt][i] = (f32x4){0.f, 0.f, 0.f, 0.f};
    stage_compute<64, 8>(P, WaH, WaL, w, lane, acc);
    __syncthreads();
    epilogue_tile(acc[0], ba, P, w * 2 + 0, lane);
    epilogue_tile(acc[1], ba, P, w * 2 + 1, lane);
    __syncthreads();

    #pragma unroll
    for (int mt = 0; mt < 2; ++mt)
        #pragma unroll
        for (int i = 0; i < 8; ++i) acc[mt][i] = (f32x4){0.f, 0.f, 0.f, 0.f};
    stage_compute<128, 8>(P, WbH, WbL, w, lane, acc);

    #pragma unroll
    for (int mt = 0; mt < 2; ++mt) {
        #pragma unroll
        for (int nt = 0; nt < 8; ++nt) {
            int col = nt * 16 + ln;
            float b = bb[col];
            #pragma unroll
            for (int r = 0; r < 4; ++r) {
                int row = m0 + (w * 2 + mt) * 16 + q * 4 + r;
                if (row < M) {
                    float v = fmaxf(acc[mt][nt][r] + b, 0.f);
                    H16out[(size_t)row * 128 + col] = __float2half_rn(v);
                }
            }
        }
    }
}

// conv2 MLP + head
__global__ __launch_bounds__(256, 2) void mfma_mlp_B(const __half2* __restrict__ z16,
                                                     const short* __restrict__ WaH,
                                                     const short* __restrict__ WaL,
                                                     const float* __restrict__ ba,
                                                     const short* __restrict__ WbH,
                                                     const short* __restrict__ WbL,
                                                     const float* __restrict__ bb,
                                                     const short* __restrict__ WlH,
                                                     const short* __restrict__ WlL,
                                                     const float* __restrict__ bl,
                                                     float* __restrict__ Out, int M) {
    __shared__ unsigned P[8 * 4 * 8 * 66];   // 67584 B
    const int t = threadIdx.x;
    const int w = t >> 6, lane = t & 63;
    const int m0 = blockIdx.x * 128;
    const int q = lane >> 4, ln = lane & 15;

    stage_global16<128>(z16, M, m0, P, t);
    __syncthreads();

    f32x4 acc[2][8];
    #pragma unroll
    for (int mt = 0; mt < 2; ++mt)
        #pragma unroll
        for (int i = 0; i < 8; ++i) acc[mt][i] = (f32x4){0.f, 0.f, 0.f, 0.f};
    stage_compute<128, 8>(P, WaH, WaL, w, lane, acc);
    __syncthreads();
    epilogue_tile(acc[0], ba, P, w * 2 + 0, lane);
    epilogue_tile(acc[1], ba, P, w * 2 + 1, lane);
    __syncthreads();

    #pragma unroll
    for (int mt = 0; mt < 2; ++mt)
        #pragma unroll
        for (int i = 0; i < 8; ++i) acc[mt][i] = (f32x4){0.f, 0.f, 0.f, 0.f};
    stage_compute<128, 8>(P, WbH, WbL, w, lane, acc);
    __syncthreads();
    epilogue_tile(acc[0], bb, P, w * 2 + 0, lane);
    epilogue_tile(acc[1], bb, P, w * 2 + 1, lane);
    __syncthreads();

    #pragma unroll
    for (int mt = 0; mt < 2; ++mt)
        #pragma unroll
        for (int i = 0; i < 8; ++i) acc[mt][i] = (f32x4){0.f, 0.f, 0.f, 0.f};
    stage_compute<128, 4>(P, WlH, WlL, w, lane, acc);

    #pragma unroll
    for (int mt = 0; mt < 2; ++mt) {
        #pragma unroll
        for (int nt = 0; nt < 4; ++nt) {
            int col = nt * 16 + ln;
            float b = bl[col];
            #pragma unroll
            for (int r = 0; r < 4; ++r) {
                int row = m0 + (w * 2 + mt) * 16 + q * 4 + r;
                if (row < M) Out[(size_t)row * 64 + col] = acc[mt][nt][r] + b;
            }
        }
    }
}

// ---------------------------------------------------------------------------

extern "C" void kernel_launch(void* const* d_in, const int* in_sizes, int n_in,
                              void* d_out, int out_size, void* d_ws, size_t ws_size,
                              hipStream_t stream) {
    const float* x    = (const float*)d_in[0];
    const int*   ei   = (const int*)d_in[1];
    const float* W1a  = (const float*)d_in[2];
    const float* b1a  = (const float*)d_in[3];
    const float* W1b  = (const float*)d_in[4];
    const float* b1b  = (const float*)d_in[5];
    const float* W2a  = (const float*)d_in[6];
    const float* b2a  = (const float*)d_in[7];
    const float* W2b  = (const float*)d_in[8];
    const float* b2b  = (const float*)d_in[9];
    const float* Wlin = (const float*)d_in[10];
    const float* blin = (const float*)d_in[11];
    float* out = (float*)d_out;

    const int N = in_sizes[0] / 64;   // 100000
    const int E = in_sizes[1] / 2;    // 1600000
    const int NBUCK = (N + BUCKET_NODES - 1) >> BUCKET_SHIFT;  // 196

    // workspace layout
    char* ws = (char*)d_ws;
    const size_t bufBytes = (size_t)N * 128 * sizeof(float);  // 51.2 MB
    __half2* Zbuf = (__half2*)(ws + 0);          // fp16 z (<=25.6 MB)
    char* B = ws + bufBytes;
    size_t off = 3 * bufBytes;
    int* row_start = (int*)(ws + off); off += ((size_t)(N + 1) * 4 + 15) & ~(size_t)15;
    int* cnt       = (int*)(ws + off); off += ((size_t)N * 4 + 15) & ~(size_t)15;
    int* partials  = (int*)(ws + off); off += 4096;
    int* gcur      = (int*)(ws + off); off += 4096;
    int* edge_src  = (int*)(ws + off); off += (size_t)E * 4;
    __half* h116   = (__half*)(ws + off); off += (size_t)N * 128 * 2;  // 25.6 MB
    // B-buffer interior aliases:
    int* gpk = (int*)B;                              // [0 .. 8MB)
    short* wHi = (short*)(B + (32u << 20));
    short* wLo = wHi + 65536;
    __half* x16 = (__half*)(B + (36u << 20));
    short* w1aH = wHi + 0;     short* w1aL = wLo + 0;
    short* w1bH = wHi + 8192;  short* w1bL = wLo + 8192;
    short* w2aH = wHi + 24576; short* w2aL = wLo + 24576;
    short* w2bH = wHi + 40960; short* w2bL = wLo + 40960;
    short* wlH  = wHi + 57344; short* wlL  = wLo + 57344;

    const int NB_N = (N + 255) / 256;          // 391
    const int NB_G = (N + 127) / 128;          // 782 MLP blocks
    const int NB_S = (E + EPB - 1) / EPB;      // 391 scatter blocks
    const int NB_A128 = (N + 3) / 4;           // 25000
    const int NB_A64  = (N + 7) / 8;           // 12500
    const int NB_P = 12500;                    // prep blocks

    // 0. merged prep: weights, x->fp16, gcur init
    prep_kernel<<<NB_P, 256, 0, stream>>>(W1a, W1b, W2a, W2b, Wlin, wHi, wLo,
                                          x, (__half2*)x16, N * 32, gcur, NBUCK);

    // 1. CSR build, bucket-binned, packed staging (LDS-local tail)
    bucket_scatter_kernel<<<NB_S, 256, 0, stream>>>(ei, E, gcur, gpk, NBUCK);
    bucket_hist_kernel<<<NBUCK, 256, 0, stream>>>(gpk, gcur, cnt, N);
    scan_block_kernel<<<NB_N, 256, 0, stream>>>(cnt, row_start, partials, N);
    scan_partials_kernel<<<1, 512, 0, stream>>>(partials, NB_N);
    scan_add_kernel<<<NB_N, 256, 0, stream>>>(row_start, partials, N, E);
    bucket_fill_kernel<<<NBUCK, 256, 0, stream>>>(gpk, gcur, row_start, edge_src, N);

    // 2. conv1: fp16 agg + MFMA MLP
    agg64_fp16<<<NB_A64, 256, 0, stream>>>((const __half2*)x16, row_start, edge_src, Zbuf, N);
    mfma_mlp_A<<<NB_G, 256, 0, stream>>>(Zbuf, w1aH, w1aL, b1a, w1bH, w1bL, b1b, h116, N);

    // 3. conv2 + head
    agg128_fp16<<<NB_A128, 256, 0, stream>>>((const __half2*)h116, row_start, edge_src, Zbuf, N);
    mfma_mlp_B<<<NB_G, 256, 0, stream>>>(Zbuf, w2aH, w2aL, b2a, w2bH, w2bL, b2b,
                                         wlH, wlL, blin, out, N);
}